// Round 6
// baseline (183.864 us; speedup 1.0000x reference)
//
#include <hip/hip_runtime.h>
#include <hip/hip_bf16.h>
#include <stdint.h>

typedef unsigned int u32;
typedef unsigned short u16;
typedef __attribute__((ext_vector_type(8))) short short8;   // 8 bf16 (MFMA A/B frag)
typedef __attribute__((ext_vector_type(4))) float floatx4;  // MFMA C/D frag

#define N_DIM 1024       // ROW*Y_ROW (output features)
#define K_DIM 1024       // COL*Z_COL (input features)
#define M_DIM 16384      // BATCH*SEQ
#define EPW  68          // epilogue LDS row stride in words (64 fp32 + 4 pad)

__device__ __forceinline__ u32 pack4(uint4 v) {
    return (v.x & 0xffu) | ((v.y & 0xffu) << 8) | ((v.z & 0xffu) << 16) | (v.w << 24);
}

__device__ __forceinline__ u16 bf16rne(float f) {
    u32 u = __float_as_uint(f);
    return (u16)((u + 0x7fffu + ((u >> 16) & 1u)) >> 16);
}

// async global->LDS, 16B per lane. LDS dest must be wave-uniform base + lane*16.
__device__ __forceinline__ void load16_lds(const void* g, void* l) {
    __builtin_amdgcn_global_load_lds(
        (const __attribute__((address_space(1))) void*)g,
        (__attribute__((address_space(3))) void*)l, 16, 0, 0);
}

// ---------------------------------------------------------------------------
// build_w: W[n,k] (bf16, row-major [N_DIM][K_DIM], n=r*128+y, k=c*128+z)
//   = d + sum_bit( a*popcnt(Y&Z) + b*Ysum + c*Zsum )
// Uniform runtime detection of uint8 vs int32-widened packed inputs.
// Grid: 256 blocks = (r,c) x z-quarter, 256 threads.
// ---------------------------------------------------------------------------
__global__ __launch_bounds__(256) void build_w(
        const u32* __restrict__ yp, const u32* __restrict__ zp,
        const int* __restrict__ ysum, const int* __restrict__ zsum,
        const float* __restrict__ pa, const float* __restrict__ pb,
        const float* __restrict__ pc, const float* __restrict__ pd,
        __hip_bfloat16* __restrict__ Wb) {
    __shared__ u32 sY[4096];   // [bit][y][t] words (16 KiB)
    __shared__ u32 sZ[1024];   // [bit][zl][t] words (4 KiB)
    __shared__ int sYs[512];
    __shared__ int sZs[128];

    const int tid = threadIdx.x;
    const int rc = blockIdx.x >> 2;
    const int zq = blockIdx.x & 3;
    const int r = rc >> 3, c = rc & 7;
    const int z0 = zq * 32;

    // uniform mode detect (32 logical bytes vs Y_sum[0])
    const uint4 d0 = ((const uint4*)yp)[0], d1 = ((const uint4*)yp)[1];
    const int sdet = __popc(d0.x) + __popc(d0.y) + __popc(d0.z) + __popc(d0.w)
                   + __popc(d1.x) + __popc(d1.y) + __popc(d1.z) + __popc(d1.w);
    const bool widened = (sdet != ysum[0]);

    if (!widened) {
#pragma unroll
        for (int j = 0; j < 4; ++j) {
            const int chunk = tid + j * 256;
            const int f = chunk * 4;                    // logical word id in block
            const int bit = f >> 10, rem = f & 1023;
            const u32 gw = (u32)((bit * 64 + r * 8 + c) * 1024 + rem);
            ((uint4*)sY)[chunk] = *(const uint4*)(yp + gw);
        }
        {
            const int f = tid * 4;
            const int bit = f >> 8;
            const u32 gw = (u32)((bit * 64 + r * 8 + c) * 1024 + z0 * 8 + (f & 255));
            ((uint4*)sZ)[tid] = *(const uint4*)(zp + gw);
        }
    } else {
#pragma unroll
        for (int j = 0; j < 4; ++j) {
            const int chunk = tid + j * 256;
            const int f = chunk * 4;
            const int bit = f >> 10, rem = f & 1023;
            const u32 gw = (u32)((bit * 64 + r * 8 + c) * 1024 + rem);
            uint4 o;
            o.x = pack4(((const uint4*)yp)[gw + 0]);
            o.y = pack4(((const uint4*)yp)[gw + 1]);
            o.z = pack4(((const uint4*)yp)[gw + 2]);
            o.w = pack4(((const uint4*)yp)[gw + 3]);
            ((uint4*)sY)[chunk] = o;
        }
        {
            const int f = tid * 4;
            const int bit = f >> 8;
            const u32 gw = (u32)((bit * 64 + r * 8 + c) * 1024 + z0 * 8 + (f & 255));
            uint4 o;
            o.x = pack4(((const uint4*)zp)[gw + 0]);
            o.y = pack4(((const uint4*)zp)[gw + 1]);
            o.z = pack4(((const uint4*)zp)[gw + 2]);
            o.w = pack4(((const uint4*)zp)[gw + 3]);
            ((uint4*)sZ)[tid] = o;
        }
    }
    for (int j = tid; j < 512; j += 256) {
        const int bit = j >> 7, y = j & 127;
        sYs[j] = ysum[((bit * 8 + r) * 8 + c) * 128 + y];
    }
    if (tid < 128) {
        const int bit = tid >> 5, zl = tid & 31;
        sZs[tid] = zsum[((bit * 8 + r) * 8 + c) * 128 + z0 + zl];
    }
    __syncthreads();

    float av[4], bv[4], cv[4];
#pragma unroll
    for (int bit = 0; bit < 4; ++bit) { av[bit] = pa[bit]; bv[bit] = pb[bit]; cv[bit] = pc[bit]; }
    const float dv = pd[0];

    const int y = tid & 127;
    const int zh = tid >> 7;       // 0/1 -> 16 z each

    u32 yw[4][8];
    float base = dv;
#pragma unroll
    for (int bit = 0; bit < 4; ++bit) {
        const uint4 q0 = ((const uint4*)sY)[bit * 256 + y * 2];
        const uint4 q1 = ((const uint4*)sY)[bit * 256 + y * 2 + 1];
        yw[bit][0] = q0.x; yw[bit][1] = q0.y; yw[bit][2] = q0.z; yw[bit][3] = q0.w;
        yw[bit][4] = q1.x; yw[bit][5] = q1.y; yw[bit][6] = q1.z; yw[bit][7] = q1.w;
        base += bv[bit] * (float)sYs[bit * 128 + y];
    }

    const int m = r * 128 + y;
#pragma unroll
    for (int zl2 = 0; zl2 < 16; ++zl2) {
        const int zl = zh * 16 + zl2;
        float wv = base;
#pragma unroll
        for (int bit = 0; bit < 4; ++bit) {
            const uint4 zw0 = ((const uint4*)sZ)[bit * 64 + zl * 2];
            const uint4 zw1 = ((const uint4*)sZ)[bit * 64 + zl * 2 + 1];
            int p = 0;
            p += __popc(yw[bit][0] & zw0.x);
            p += __popc(yw[bit][1] & zw0.y);
            p += __popc(yw[bit][2] & zw0.z);
            p += __popc(yw[bit][3] & zw0.w);
            p += __popc(yw[bit][4] & zw1.x);
            p += __popc(yw[bit][5] & zw1.y);
            p += __popc(yw[bit][6] & zw1.z);
            p += __popc(yw[bit][7] & zw1.w);
            wv += av[bit] * (float)p + cv[bit] * (float)sZs[bit * 32 + zl];
        }
        const int k = c * 128 + z0 + zl;
        Wb[(size_t)m * K_DIM + k] = __float2bfloat16(wv);
    }
}

// ---------------------------------------------------------------------------
// gemm_bias: out[M,N] = X[M,K](fp32, converted in-kernel) * Wb[N,K]^T + bias
//
// 256(M) x 128(N) tile, BK=32, 256 threads = 4 waves (2M x 2N), per-wave
// 128x64. Double-buffered LDS 2 x 24 KB = 48 KB static -> 2 blocks/CU.
// convert_x is FUSED: A-staging reg-loads fp32 X, converts to bf16 (RNE,
// bit-identical to prior convert_x), ds_writes into the swizzled layout.
// Per K-tile:
//   P1: 12 ds_read_b128 (a[0..7], b[0..3]); bar; lgkmcnt(0); prio1;
//       16 MFMA (ni 0,1); prio0; bar
//   P2: issue Areg(t+2) 8x global_load_dwordx4 + B(t+2) 2x global_load_lds;
//       prio1; 16 MFMA (ni 2,3); prio0; vmcnt(2); cvt+4x ds_write_b128; bar
// Safety: P1 lgkm0 before its closing barrier drains ALL slot-s reads ->
// P2's slot-s ds_writes are WAR-safe. A(t+2) writes drained by each wave's
// t+1 P1 lgkm0, two barriers before t+2 P1 reads.
// vmcnt ledger: at tile t's vmcnt(2), queue = B(t+1)[2] + Areg(t+2)[8] +
// B(t+2)[2]; wait-to-2 retires B(t+1) (needed by t+1 P1, before this tile's
// closing barrier) and Areg(t+2) (needed by cvt now); leaves B(t+2).
// Tail tiles 30/31: no stage, vmcnt(0) (2nd is a no-op).
// A-stage decomposition: thread t, j=0..3: row=j*64+(t>>2), chunk ck=t&3
// (8 fp32 = 16B bf16); global: 4-lane groups read 128B contiguous, 16 rows
// per instruction. LDS write byte = (row>>4)*1024 + (row&15)*64 +
// (ck^((row>>1)&3))*16 -- the same swizzle the ds_read side uses
// (cx = (fq^((fm>>1)&3))*16); 64 lanes cover 1024 consecutive bytes.
// Grid dim3(64,8): XCD = x%8 -> all 8 ntiles of an mtile on one XCD; X
// panel (1 MB fp32) fetched from HBM once, L2-served to the other 7.
// ---------------------------------------------------------------------------
__device__ __forceinline__ void stage_b32(const u16* __restrict__ Wb,
        int n0, int kt, char* slot, int w, int lane, int srow, int csrc) {
#pragma unroll
    for (int j = 0; j < 2; ++j) {
        const int slab = w * 2 + j;               // 0..7
        const int row = slab * 16 + srow;         // 0..127
        load16_lds(Wb + (size_t)(n0 + row) * K_DIM + kt * 32 + csrc * 8,
                   slot + 16384 + slab * 1024 + lane * 16);
    }
}

__device__ __forceinline__ void load_a32(const float* __restrict__ X,
        int m0, int kt, int tid, float4 (&ar)[4][2]) {
#pragma unroll
    for (int j = 0; j < 4; ++j) {
        const int row = j * 64 + (tid >> 2);      // 0..255
        const float* p = X + (size_t)(m0 + row) * K_DIM + kt * 32 + (tid & 3) * 8;
        ar[j][0] = *(const float4*)p;
        ar[j][1] = *(const float4*)(p + 4);
    }
}

__device__ __forceinline__ void cvt_write_a32(char* slot, int tid,
        const float4 (&ar)[4][2]) {
    const int ck = tid & 3;
#pragma unroll
    for (int j = 0; j < 4; ++j) {
        const int row = j * 64 + (tid >> 2);
        short8 v;
        v[0] = (short)bf16rne(ar[j][0].x); v[1] = (short)bf16rne(ar[j][0].y);
        v[2] = (short)bf16rne(ar[j][0].z); v[3] = (short)bf16rne(ar[j][0].w);
        v[4] = (short)bf16rne(ar[j][1].x); v[5] = (short)bf16rne(ar[j][1].y);
        v[6] = (short)bf16rne(ar[j][1].z); v[7] = (short)bf16rne(ar[j][1].w);
        *(short8*)(slot + ((row >> 4) << 10) + ((row & 15) << 6)
                        + ((ck ^ ((row >> 1) & 3)) << 4)) = v;
    }
}

template<bool DO_STAGE>
__device__ __forceinline__ void tile32(const char* __restrict__ slot,
        char* stslot, int ktg, floatx4 (&acc)[8][4],
        const float* __restrict__ X, const u16* __restrict__ Wb,
        int m0, int n0, int tid, int w, int lane, int srow, int csrc,
        int wr, int wc, int fm, int cx) {
    const char* As = slot;
    const char* Bs = slot + 16384;
    short8 a[8], b[4];

    // ---- P1 ----
#pragma unroll
    for (int mi = 0; mi < 8; ++mi)
        a[mi] = *(const short8*)(As + (wr * 128 + mi * 16 + fm) * 64 + cx);
#pragma unroll
    for (int ni = 0; ni < 4; ++ni)
        b[ni] = *(const short8*)(Bs + (wc * 64 + ni * 16 + fm) * 64 + cx);
    __builtin_amdgcn_s_barrier();
    asm volatile("s_waitcnt lgkmcnt(0)" ::: "memory");
    __builtin_amdgcn_s_setprio(1);
#pragma unroll
    for (int mi = 0; mi < 8; ++mi) {
        acc[mi][0] = __builtin_amdgcn_mfma_f32_16x16x32_bf16(a[mi], b[0], acc[mi][0], 0, 0, 0);
        acc[mi][1] = __builtin_amdgcn_mfma_f32_16x16x32_bf16(a[mi], b[1], acc[mi][1], 0, 0, 0);
    }
    __builtin_amdgcn_s_setprio(0);
    __builtin_amdgcn_s_barrier();

    // ---- P2 ----
    float4 ar[4][2];
    if (DO_STAGE) {
        load_a32(X, m0, ktg, tid, ar);                       // 8 vmem -> regs
        stage_b32(Wb, n0, ktg, stslot, w, lane, srow, csrc); // 2 gload_lds
    }
    __builtin_amdgcn_s_setprio(1);
#pragma unroll
    for (int mi = 0; mi < 8; ++mi) {
        acc[mi][2] = __builtin_amdgcn_mfma_f32_16x16x32_bf16(a[mi], b[2], acc[mi][2], 0, 0, 0);
        acc[mi][3] = __builtin_amdgcn_mfma_f32_16x16x32_bf16(a[mi], b[3], acc[mi][3], 0, 0, 0);
    }
    __builtin_amdgcn_s_setprio(0);
    if (DO_STAGE) {
        asm volatile("s_waitcnt vmcnt(2)" ::: "memory");  // retire B(t+1)+Areg
        cvt_write_a32(stslot, tid, ar);
    } else {
        asm volatile("s_waitcnt vmcnt(0)" ::: "memory");
    }
    __builtin_amdgcn_s_barrier();
}

__global__ __launch_bounds__(256, 2) void gemm_bias(
        const float* __restrict__ X, const u16* __restrict__ Wb,
        const float* __restrict__ bias, float* __restrict__ out) {
    __shared__ char lds[49152];    // slot s at s*24576: A[256][32] then B[128][32]

    const int tid = threadIdx.x;
    const int lane = tid & 63;
    const int w = tid >> 6;          // wave 0..3
    const int wr = w >> 1;           // 0..1 (M)
    const int wc = w & 1;            // 0..1 (N)
    const int m0 = blockIdx.x * 256;
    const int n0 = blockIdx.y * 128;

    // B staging lane decomposition: 64 lanes cover one 1-KB slab (16r x 4c)
    const int srow = lane >> 2;                        // 0..15
    const int csrc = (lane & 3) ^ ((lane >> 3) & 3);   // swizzled source chunk
    // fragment lanes
    const int fm = lane & 15, fq = lane >> 4;
    const int cx = (fq ^ ((fm >> 1) & 3)) * 16;        // swizzled byte col

    char* slot0 = lds;
    char* slot1 = lds + 24576;

    floatx4 acc[8][4] = {};

    // prologue: A(0),A(1) via reg+cvt; B(0),B(1) via gload_lds; full drain.
    {
        float4 ar[4][2];
        load_a32(X, m0, 0, tid, ar);                        // 8
        stage_b32(Wb, n0, 0, slot0, w, lane, srow, csrc);   // 2
        stage_b32(Wb, n0, 1, slot1, w, lane, srow, csrc);   // 2
        asm volatile("s_waitcnt vmcnt(4)" ::: "memory");    // Areg(0) done
        cvt_write_a32(slot0, tid, ar);
        load_a32(X, m0, 1, tid, ar);
        asm volatile("s_waitcnt vmcnt(0)" ::: "memory");    // all done
        cvt_write_a32(slot1, tid, ar);
    }
    __syncthreads();   // A-writes drained (lgkm0); both tiles resident

    for (int it = 0; it < 15; ++it) {
        tile32<true>(slot0, slot0, 2 * it + 2, acc, X, Wb, m0, n0,
                     tid, w, lane, srow, csrc, wr, wc, fm, cx);
        tile32<true>(slot1, slot1, 2 * it + 3, acc, X, Wb, m0, n0,
                     tid, w, lane, srow, csrc, wr, wc, fm, cx);
    }
    // tail: tiles 30, 31 -- no staging, conservative drains
    tile32<false>(slot0, slot0, 0, acc, X, Wb, m0, n0,
                  tid, w, lane, srow, csrc, wr, wc, fm, cx);
    tile32<false>(slot1, slot1, 0, acc, X, Wb, m0, n0,
                  tid, w, lane, srow, csrc, wr, wc, fm, cx);

    // -----------------------------------------------------------------------
    // Epilogue: D layout col(N)=lane&15, row(M)=(lane>>4)*4+reg.
    // Per-wave private LDS slice (16 x EPW fp32): transpose to row-major,
    // store float4 (256 B contiguous per 16-lane group).
    // -----------------------------------------------------------------------
    float bias_r[4];
#pragma unroll
    for (int ni = 0; ni < 4; ++ni)
        bias_r[ni] = bias[n0 + wc * 64 + ni * 16 + fm];

    __syncthreads();   // all waves done with both slots; no vm loads pending
    float* ep = (float*)lds + w * (16 * EPW);   // 4352 B per wave, 17.4 KB total
    const int gm0 = m0 + wr * 128;
    const int gn0 = n0 + wc * 64;

#pragma unroll
    for (int mi = 0; mi < 8; ++mi) {
#pragma unroll
        for (int ni = 0; ni < 4; ++ni)
#pragma unroll
            for (int reg = 0; reg < 4; ++reg)
                ep[(fq * 4 + reg) * EPW + ni * 16 + fm] = acc[mi][ni][reg] + bias_r[ni];
#pragma unroll
        for (int t = 0; t < 4; ++t) {
            const int lr = t * 4 + fq;               // local row 0..15
            const float4 v = *(const float4*)(ep + lr * EPW + fm * 4);
            *(float4*)(out + (size_t)(gm0 + mi * 16 + lr) * N_DIM + gn0 + fm * 4) = v;
        }
        // wave-private slice; DS pipe is in-order per wave -> WAR safe
    }
}

// ---------------------------------------------------------------------------
extern "C" void kernel_launch(void* const* d_in, const int* in_sizes, int n_in,
                              void* d_out, int out_size, void* d_ws, size_t ws_size,
                              hipStream_t stream) {
    const float* X   = (const float*)d_in[0];
    const u32*   Yp  = (const u32*)d_in[1];
    const u32*   Zp  = (const u32*)d_in[2];
    const int*   Ys  = (const int*)d_in[3];
    const int*   Zs  = (const int*)d_in[4];
    const float* pa  = (const float*)d_in[5];
    const float* pb  = (const float*)d_in[6];
    const float* pc  = (const float*)d_in[7];
    const float* pd  = (const float*)d_in[8];
    const float* bias = (const float*)d_in[9];
    float* out = (float*)d_out;

    char* ws = (char*)d_ws;
    __hip_bfloat16* Wb = (__hip_bfloat16*)ws;                 // 2 MiB

    build_w<<<256, 256, 0, stream>>>(Yp, Zp, Ys, Zs, pa, pb, pc, pd, Wb);
    gemm_bias<<<dim3(64, 8), 256, 0, stream>>>(X, (const u16*)Wb, bias, out);
}

// Round 7
// 181.924 us; speedup vs baseline: 1.0107x; 1.0107x over previous
//
#include <hip/hip_runtime.h>
#include <hip/hip_bf16.h>
#include <stdint.h>

typedef unsigned int u32;
typedef unsigned short u16;
typedef __attribute__((ext_vector_type(8))) short short8;   // 8 bf16 (MFMA A/B frag)
typedef __attribute__((ext_vector_type(4))) float floatx4;  // MFMA C/D frag

#define N_DIM 1024       // ROW*Y_ROW (output features)
#define K_DIM 1024       // COL*Z_COL (input features)
#define M_DIM 16384      // BATCH*SEQ
#define EPW  68          // epilogue LDS row stride in words (64 fp32 + 4 pad)

__device__ __forceinline__ u32 pack4(uint4 v) {
    return (v.x & 0xffu) | ((v.y & 0xffu) << 8) | ((v.z & 0xffu) << 16) | (v.w << 24);
}

__device__ __forceinline__ u16 bf16rne(float f) {
    u32 u = __float_as_uint(f);
    return (u16)((u + 0x7fffu + ((u >> 16) & 1u)) >> 16);
}

// async global->LDS, 16B per lane. LDS dest must be wave-uniform base + lane*16.
__device__ __forceinline__ void load16_lds(const void* g, void* l) {
    __builtin_amdgcn_global_load_lds(
        (const __attribute__((address_space(1))) void*)g,
        (__attribute__((address_space(3))) void*)l, 16, 0, 0);
}

// ---------------------------------------------------------------------------
// prep: merged build_w (blocks 0..255) + convert_x (blocks 256..8447).
// (verbatim round-5 version: passed at 169.6 us)
// ---------------------------------------------------------------------------
__global__ __launch_bounds__(256) void prep(
        const u32* __restrict__ yp, const u32* __restrict__ zp,
        const int* __restrict__ ysum, const int* __restrict__ zsum,
        const float* __restrict__ pa, const float* __restrict__ pb,
        const float* __restrict__ pc, const float* __restrict__ pd,
        __hip_bfloat16* __restrict__ Wb,
        const float4* __restrict__ X, ushort4* __restrict__ Xb) {
    __shared__ u32 sY[4096];   // [bit][y][t] words (16 KiB)
    __shared__ u32 sZ[1024];   // [bit][zl][t] words (4 KiB)
    __shared__ int sYs[512];
    __shared__ int sZs[128];

    const int tid = threadIdx.x;

    if (blockIdx.x >= 256) {
        // ---- convert_x: X fp32 -> bf16 (RNE), fully coalesced ----
        const size_t base = (size_t)(blockIdx.x - 256) * 512;
        const float4 a = X[base + tid];
        const float4 b = X[base + 256 + tid];
        ushort4 oa, ob;
        oa.x = bf16rne(a.x); oa.y = bf16rne(a.y); oa.z = bf16rne(a.z); oa.w = bf16rne(a.w);
        ob.x = bf16rne(b.x); ob.y = bf16rne(b.y); ob.z = bf16rne(b.z); ob.w = bf16rne(b.w);
        Xb[base + tid] = oa;
        Xb[base + 256 + tid] = ob;
        return;
    }

    // ---- build_w ----
    const int rc = blockIdx.x >> 2;
    const int zq = blockIdx.x & 3;
    const int r = rc >> 3, c = rc & 7;
    const int z0 = zq * 32;

    // uniform mode detect (32 logical bytes vs Y_sum[0])
    const uint4 d0 = ((const uint4*)yp)[0], d1 = ((const uint4*)yp)[1];
    const int sdet = __popc(d0.x) + __popc(d0.y) + __popc(d0.z) + __popc(d0.w)
                   + __popc(d1.x) + __popc(d1.y) + __popc(d1.z) + __popc(d1.w);
    const bool widened = (sdet != ysum[0]);

    if (!widened) {
#pragma unroll
        for (int j = 0; j < 4; ++j) {
            const int chunk = tid + j * 256;
            const int f = chunk * 4;                    // logical word id in block
            const int bit = f >> 10, rem = f & 1023;
            const u32 gw = (u32)((bit * 64 + r * 8 + c) * 1024 + rem);
            ((uint4*)sY)[chunk] = *(const uint4*)(yp + gw);
        }
        {
            const int f = tid * 4;
            const int bit = f >> 8;
            const u32 gw = (u32)((bit * 64 + r * 8 + c) * 1024 + z0 * 8 + (f & 255));
            ((uint4*)sZ)[tid] = *(const uint4*)(zp + gw);
        }
    } else {
#pragma unroll
        for (int j = 0; j < 4; ++j) {
            const int chunk = tid + j * 256;
            const int f = chunk * 4;
            const int bit = f >> 10, rem = f & 1023;
            const u32 gw = (u32)((bit * 64 + r * 8 + c) * 1024 + rem);
            uint4 o;
            o.x = pack4(((const uint4*)yp)[gw + 0]);
            o.y = pack4(((const uint4*)yp)[gw + 1]);
            o.z = pack4(((const uint4*)yp)[gw + 2]);
            o.w = pack4(((const uint4*)yp)[gw + 3]);
            ((uint4*)sY)[chunk] = o;
        }
        {
            const int f = tid * 4;
            const int bit = f >> 8;
            const u32 gw = (u32)((bit * 64 + r * 8 + c) * 1024 + z0 * 8 + (f & 255));
            uint4 o;
            o.x = pack4(((const uint4*)zp)[gw + 0]);
            o.y = pack4(((const uint4*)zp)[gw + 1]);
            o.z = pack4(((const uint4*)zp)[gw + 2]);
            o.w = pack4(((const uint4*)zp)[gw + 3]);
            ((uint4*)sZ)[tid] = o;
        }
    }
    for (int j = tid; j < 512; j += 256) {
        const int bit = j >> 7, y = j & 127;
        sYs[j] = ysum[((bit * 8 + r) * 8 + c) * 128 + y];
    }
    if (tid < 128) {
        const int bit = tid >> 5, zl = tid & 31;
        sZs[tid] = zsum[((bit * 8 + r) * 8 + c) * 128 + z0 + zl];
    }
    __syncthreads();

    float av[4], bv[4], cv[4];
#pragma unroll
    for (int bit = 0; bit < 4; ++bit) { av[bit] = pa[bit]; bv[bit] = pb[bit]; cv[bit] = pc[bit]; }
    const float dv = pd[0];

    const int y = tid & 127;
    const int zh = tid >> 7;       // 0/1 -> 16 z each

    u32 yw[4][8];
    float base = dv;
#pragma unroll
    for (int bit = 0; bit < 4; ++bit) {
        const uint4 q0 = ((const uint4*)sY)[bit * 256 + y * 2];
        const uint4 q1 = ((const uint4*)sY)[bit * 256 + y * 2 + 1];
        yw[bit][0] = q0.x; yw[bit][1] = q0.y; yw[bit][2] = q0.z; yw[bit][3] = q0.w;
        yw[bit][4] = q1.x; yw[bit][5] = q1.y; yw[bit][6] = q1.z; yw[bit][7] = q1.w;
        base += bv[bit] * (float)sYs[bit * 128 + y];
    }

    const int m = r * 128 + y;
#pragma unroll
    for (int zl2 = 0; zl2 < 16; ++zl2) {
        const int zl = zh * 16 + zl2;
        float wv = base;
#pragma unroll
        for (int bit = 0; bit < 4; ++bit) {
            const uint4 zw0 = ((const uint4*)sZ)[bit * 64 + zl * 2];
            const uint4 zw1 = ((const uint4*)sZ)[bit * 64 + zl * 2 + 1];
            int p = 0;
            p += __popc(yw[bit][0] & zw0.x);
            p += __popc(yw[bit][1] & zw0.y);
            p += __popc(yw[bit][2] & zw0.z);
            p += __popc(yw[bit][3] & zw0.w);
            p += __popc(yw[bit][4] & zw1.x);
            p += __popc(yw[bit][5] & zw1.y);
            p += __popc(yw[bit][6] & zw1.z);
            p += __popc(yw[bit][7] & zw1.w);
            wv += av[bit] * (float)p + cv[bit] * (float)sZs[bit * 32 + zl];
        }
        const int k = c * 128 + z0 + zl;
        Wb[(size_t)m * K_DIM + k] = __float2bfloat16(wv);
    }
}

// ---------------------------------------------------------------------------
// gemm_bias: out[M,N] = Xb[M,K] * Wb[N,K]^T + bias[N]   (bf16 MFMA, fp32 out)
//
// 256(M) x 128(N) tile, BK=32, 256 threads = 4 waves (2M x 2N), per-wave
// 128x64. A staged in double-buffered LDS (2 x 16 KB, swizzled, via
// global_load_lds); B fragments stream GLOBAL -> REGISTERS (W panel is
// 2 MB, L2/L1-hot; removes 1/3 of LDS read traffic and all B LDS writes),
// prefetched one tile ahead into a compile-time double buffer bA/bB.
// Per K-tile t:
//   P1: 8 ds_read_b128 (a[0..7]); bar; lgkmcnt(0); prio1;
//       16 MFMA (a x bcur[0,1]); prio0; bar
//   P2: load b(t+1) -> bnext (4 x global dwordx4, reg); stage A(t+2)
//       (4 global_load_lds); prio1; 16 MFMA (a x bcur[2,3]); prio0;
//       vmcnt(4); bar
// WAR safety: every wave's lgkm0 in P1 drains its slot-s a-reads before the
// mid barrier -> P2's slot-s overwriting stage is safe.
// vmcnt ledger: before t's P2, queue = Ast(t+1)[4]; P2 issues b(t+1)[4] +
// Ast(t+2)[4] -> 12; vmcnt(4) retires the oldest 8, which ALWAYS includes
// Ast(t+1) (the only load the compiler cannot track; reg-dest b loads get
// compiler-inserted waits before MFMA use). Tails: t=30 loads b(31), no
// stage, vmcnt(0); t=31 nothing, vmcnt(0) no-op.
// A swizzle (round-5 proven): store chunk (l&3)^((l>>3)&3) via per-lane
// source; read byte col cx=(fq^((fm>>1)&3))*16.
// Grid dim3(64,8): XCD = x%8 -> all 8 ntiles of an mtile on one XCD.
// ---------------------------------------------------------------------------
__device__ __forceinline__ void stage_a(const u16* __restrict__ Xb,
        int m0, int kt, char* slot, int w, int lane, int srow, int csrc) {
#pragma unroll
    for (int j = 0; j < 4; ++j) {
        const int slab = w * 4 + j;               // 0..15
        const int row = slab * 16 + srow;         // 0..255
        load16_lds(Xb + (size_t)(m0 + row) * K_DIM + kt * 32 + csrc * 8,
                   slot + slab * 1024 + lane * 16);
    }
}

__device__ __forceinline__ void load_b(const u16* __restrict__ Wb,
        int n0, int kt, int wc, int fm, int fq, short8 (&b)[4]) {
#pragma unroll
    for (int ni = 0; ni < 4; ++ni)
        b[ni] = *(const short8*)(Wb + (size_t)(n0 + wc * 64 + ni * 16 + fm) * K_DIM
                                 + kt * 32 + fq * 8);
}

template<bool LOADB, bool STAGEA, int VM>
__device__ __forceinline__ void tile32(const char* __restrict__ slot,
        char* stslot, int tnext, int tstage, floatx4 (&acc)[8][4],
        short8 (&bcur)[4], short8 (&bnext)[4],
        const u16* __restrict__ Xb, const u16* __restrict__ Wb,
        int m0, int n0, int w, int lane, int srow, int csrc,
        int wr, int wc, int fm, int fq, int cx) {
    short8 a[8];

    // ---- P1 ----
#pragma unroll
    for (int mi = 0; mi < 8; ++mi)
        a[mi] = *(const short8*)(slot + (wr * 128 + mi * 16 + fm) * 64 + cx);
    __builtin_amdgcn_s_barrier();
    asm volatile("s_waitcnt lgkmcnt(0)" ::: "memory");
    __builtin_amdgcn_s_setprio(1);
#pragma unroll
    for (int mi = 0; mi < 8; ++mi) {
        acc[mi][0] = __builtin_amdgcn_mfma_f32_16x16x32_bf16(a[mi], bcur[0], acc[mi][0], 0, 0, 0);
        acc[mi][1] = __builtin_amdgcn_mfma_f32_16x16x32_bf16(a[mi], bcur[1], acc[mi][1], 0, 0, 0);
    }
    __builtin_amdgcn_s_setprio(0);
    __builtin_amdgcn_s_barrier();

    // ---- P2 ----
    if (LOADB)  load_b(Wb, n0, tnext, wc, fm, fq, bnext);               // 4 reg
    if (STAGEA) stage_a(Xb, m0, tstage, stslot, w, lane, srow, csrc);   // 4 lds
    __builtin_amdgcn_s_setprio(1);
#pragma unroll
    for (int mi = 0; mi < 8; ++mi) {
        acc[mi][2] = __builtin_amdgcn_mfma_f32_16x16x32_bf16(a[mi], bcur[2], acc[mi][2], 0, 0, 0);
        acc[mi][3] = __builtin_amdgcn_mfma_f32_16x16x32_bf16(a[mi], bcur[3], acc[mi][3], 0, 0, 0);
    }
    __builtin_amdgcn_s_setprio(0);
    if (VM == 4) asm volatile("s_waitcnt vmcnt(4)" ::: "memory");
    else         asm volatile("s_waitcnt vmcnt(0)" ::: "memory");
    __builtin_amdgcn_s_barrier();
}

__global__ __launch_bounds__(256, 2) void gemm_bias(
        const u16* __restrict__ Xb, const u16* __restrict__ Wb,
        const float* __restrict__ bias, float* __restrict__ out) {
    __shared__ char lds[32768];    // A slots: slot s at s*16384 (16 rows-slabs)

    const int tid = threadIdx.x;
    const int lane = tid & 63;
    const int w = tid >> 6;          // wave 0..3
    const int wr = w >> 1;           // 0..1 (M)
    const int wc = w & 1;            // 0..1 (N)
    const int m0 = blockIdx.x * 256;
    const int n0 = blockIdx.y * 128;

    // A staging lane decomposition: 64 lanes cover one 1-KB slab (16r x 4c)
    const int srow = lane >> 2;                        // 0..15
    const int csrc = (lane & 3) ^ ((lane >> 3) & 3);   // swizzled source chunk
    // fragment lanes
    const int fm = lane & 15, fq = lane >> 4;
    const int cx = (fq ^ ((fm >> 1) & 3)) * 16;        // swizzled byte col

    char* slot0 = lds;
    char* slot1 = lds + 16384;

    floatx4 acc[8][4] = {};
    short8 bA[4], bB[4];

    // prologue: A(0)->slot0, A(1)->slot1, b(0)->bA; full drain.
    stage_a(Xb, m0, 0, slot0, w, lane, srow, csrc);
    stage_a(Xb, m0, 1, slot1, w, lane, srow, csrc);
    load_b(Wb, n0, 0, wc, fm, fq, bA);
    __syncthreads();   // compiler emits vmcnt(0) lgkmcnt(0) drain before barrier

    for (int it = 0; it < 15; ++it) {
        tile32<true, true, 4>(slot0, slot0, 2 * it + 1, 2 * it + 2, acc, bA, bB,
                              Xb, Wb, m0, n0, w, lane, srow, csrc, wr, wc, fm, fq, cx);
        tile32<true, true, 4>(slot1, slot1, 2 * it + 2, 2 * it + 3, acc, bB, bA,
                              Xb, Wb, m0, n0, w, lane, srow, csrc, wr, wc, fm, fq, cx);
    }
    // tail: tile 30 (loads b(31), no A-stage), tile 31 (nothing)
    tile32<true, false, 0>(slot0, slot0, 31, 0, acc, bA, bB,
                           Xb, Wb, m0, n0, w, lane, srow, csrc, wr, wc, fm, fq, cx);
    tile32<false, false, 0>(slot1, slot1, 0, 0, acc, bB, bA,
                            Xb, Wb, m0, n0, w, lane, srow, csrc, wr, wc, fm, fq, cx);

    // -----------------------------------------------------------------------
    // Epilogue: D layout col(N)=lane&15, row(M)=(lane>>4)*4+reg.
    // Per-wave private LDS slice (16 x EPW fp32): transpose to row-major,
    // store float4 (256 B contiguous per 16-lane group).
    // -----------------------------------------------------------------------
    float bias_r[4];
#pragma unroll
    for (int ni = 0; ni < 4; ++ni)
        bias_r[ni] = bias[n0 + wc * 64 + ni * 16 + fm];

    __syncthreads();   // all waves done with both slots; no vm loads pending
    float* ep = (float*)lds + w * (16 * EPW);   // 4352 B per wave, 17.4 KB total
    const int gm0 = m0 + wr * 128;
    const int gn0 = n0 + wc * 64;

#pragma unroll
    for (int mi = 0; mi < 8; ++mi) {
#pragma unroll
        for (int ni = 0; ni < 4; ++ni)
#pragma unroll
            for (int reg = 0; reg < 4; ++reg)
                ep[(fq * 4 + reg) * EPW + ni * 16 + fm] = acc[mi][ni][reg] + bias_r[ni];
#pragma unroll
        for (int t = 0; t < 4; ++t) {
            const int lr = t * 4 + fq;               // local row 0..15
            const float4 v = *(const float4*)(ep + lr * EPW + fm * 4);
            *(float4*)(out + (size_t)(gm0 + mi * 16 + lr) * N_DIM + gn0 + fm * 4) = v;
        }
        // wave-private slice; DS pipe is in-order per wave -> WAR safe
    }
}

// ---------------------------------------------------------------------------
extern "C" void kernel_launch(void* const* d_in, const int* in_sizes, int n_in,
                              void* d_out, int out_size, void* d_ws, size_t ws_size,
                              hipStream_t stream) {
    const float* X   = (const float*)d_in[0];
    const u32*   Yp  = (const u32*)d_in[1];
    const u32*   Zp  = (const u32*)d_in[2];
    const int*   Ys  = (const int*)d_in[3];
    const int*   Zs  = (const int*)d_in[4];
    const float* pa  = (const float*)d_in[5];
    const float* pb  = (const float*)d_in[6];
    const float* pc  = (const float*)d_in[7];
    const float* pd  = (const float*)d_in[8];
    const float* bias = (const float*)d_in[9];
    float* out = (float*)d_out;

    char* ws = (char*)d_ws;
    __hip_bfloat16* Wb = (__hip_bfloat16*)ws;                 // 2 MiB
    u16*            Xb = (u16*)(ws + (2u << 20));             // 32 MiB

    prep<<<8448, 256, 0, stream>>>(Yp, Zp, Ys, Zs, pa, pb, pc, pd, Wb,
                                   (const float4*)X, (ushort4*)Xb);
    gemm_bias<<<dim3(64, 8), 256, 0, stream>>>(Xb, (const u16*)Wb, bias, out);
}

// Round 8
// 174.263 us; speedup vs baseline: 1.0551x; 1.0440x over previous
//
#include <hip/hip_runtime.h>
#include <hip/hip_bf16.h>
#include <stdint.h>

typedef unsigned int u32;
typedef unsigned short u16;
typedef __attribute__((ext_vector_type(8))) short short8;   // 8 bf16 (MFMA A/B frag)
typedef __attribute__((ext_vector_type(4))) float floatx4;  // MFMA C/D frag

#define N_DIM 1024       // ROW*Y_ROW (output features)
#define K_DIM 1024       // COL*Z_COL (input features)
#define M_DIM 16384      // BATCH*SEQ
#define EPW  68          // epilogue LDS row stride in words (64 fp32 + 4 pad)

__device__ __forceinline__ u32 pack4(uint4 v) {
    return (v.x & 0xffu) | ((v.y & 0xffu) << 8) | ((v.z & 0xffu) << 16) | (v.w << 24);
}

__device__ __forceinline__ u16 bf16rne(float f) {
    u32 u = __float_as_uint(f);
    return (u16)((u + 0x7fffu + ((u >> 16) & 1u)) >> 16);
}

// async global->LDS, 16B per lane. LDS dest must be wave-uniform base + lane*16.
__device__ __forceinline__ void load16_lds(const void* g, void* l) {
    __builtin_amdgcn_global_load_lds(
        (const __attribute__((address_space(1))) void*)g,
        (__attribute__((address_space(3))) void*)l, 16, 0, 0);
}

// ---------------------------------------------------------------------------
// prep: merged build_w (blocks 0..255) + convert_x (blocks 256..8447).
// (verbatim round-5 version: passed at 169.6 us)
// ---------------------------------------------------------------------------
__global__ __launch_bounds__(256) void prep(
        const u32* __restrict__ yp, const u32* __restrict__ zp,
        const int* __restrict__ ysum, const int* __restrict__ zsum,
        const float* __restrict__ pa, const float* __restrict__ pb,
        const float* __restrict__ pc, const float* __restrict__ pd,
        __hip_bfloat16* __restrict__ Wb,
        const float4* __restrict__ X, ushort4* __restrict__ Xb) {
    __shared__ u32 sY[4096];   // [bit][y][t] words (16 KiB)
    __shared__ u32 sZ[1024];   // [bit][zl][t] words (4 KiB)
    __shared__ int sYs[512];
    __shared__ int sZs[128];

    const int tid = threadIdx.x;

    if (blockIdx.x >= 256) {
        // ---- convert_x: X fp32 -> bf16 (RNE), fully coalesced ----
        const size_t base = (size_t)(blockIdx.x - 256) * 512;
        const float4 a = X[base + tid];
        const float4 b = X[base + 256 + tid];
        ushort4 oa, ob;
        oa.x = bf16rne(a.x); oa.y = bf16rne(a.y); oa.z = bf16rne(a.z); oa.w = bf16rne(a.w);
        ob.x = bf16rne(b.x); ob.y = bf16rne(b.y); ob.z = bf16rne(b.z); ob.w = bf16rne(b.w);
        Xb[base + tid] = oa;
        Xb[base + 256 + tid] = ob;
        return;
    }

    // ---- build_w ----
    const int rc = blockIdx.x >> 2;
    const int zq = blockIdx.x & 3;
    const int r = rc >> 3, c = rc & 7;
    const int z0 = zq * 32;

    // uniform mode detect (32 logical bytes vs Y_sum[0])
    const uint4 d0 = ((const uint4*)yp)[0], d1 = ((const uint4*)yp)[1];
    const int sdet = __popc(d0.x) + __popc(d0.y) + __popc(d0.z) + __popc(d0.w)
                   + __popc(d1.x) + __popc(d1.y) + __popc(d1.z) + __popc(d1.w);
    const bool widened = (sdet != ysum[0]);

    if (!widened) {
#pragma unroll
        for (int j = 0; j < 4; ++j) {
            const int chunk = tid + j * 256;
            const int f = chunk * 4;                    // logical word id in block
            const int bit = f >> 10, rem = f & 1023;
            const u32 gw = (u32)((bit * 64 + r * 8 + c) * 1024 + rem);
            ((uint4*)sY)[chunk] = *(const uint4*)(yp + gw);
        }
        {
            const int f = tid * 4;
            const int bit = f >> 8;
            const u32 gw = (u32)((bit * 64 + r * 8 + c) * 1024 + z0 * 8 + (f & 255));
            ((uint4*)sZ)[tid] = *(const uint4*)(zp + gw);
        }
    } else {
#pragma unroll
        for (int j = 0; j < 4; ++j) {
            const int chunk = tid + j * 256;
            const int f = chunk * 4;
            const int bit = f >> 10, rem = f & 1023;
            const u32 gw = (u32)((bit * 64 + r * 8 + c) * 1024 + rem);
            uint4 o;
            o.x = pack4(((const uint4*)yp)[gw + 0]);
            o.y = pack4(((const uint4*)yp)[gw + 1]);
            o.z = pack4(((const uint4*)yp)[gw + 2]);
            o.w = pack4(((const uint4*)yp)[gw + 3]);
            ((uint4*)sY)[chunk] = o;
        }
        {
            const int f = tid * 4;
            const int bit = f >> 8;
            const u32 gw = (u32)((bit * 64 + r * 8 + c) * 1024 + z0 * 8 + (f & 255));
            uint4 o;
            o.x = pack4(((const uint4*)zp)[gw + 0]);
            o.y = pack4(((const uint4*)zp)[gw + 1]);
            o.z = pack4(((const uint4*)zp)[gw + 2]);
            o.w = pack4(((const uint4*)zp)[gw + 3]);
            ((uint4*)sZ)[tid] = o;
        }
    }
    for (int j = tid; j < 512; j += 256) {
        const int bit = j >> 7, y = j & 127;
        sYs[j] = ysum[((bit * 8 + r) * 8 + c) * 128 + y];
    }
    if (tid < 128) {
        const int bit = tid >> 5, zl = tid & 31;
        sZs[tid] = zsum[((bit * 8 + r) * 8 + c) * 128 + z0 + zl];
    }
    __syncthreads();

    float av[4], bv[4], cv[4];
#pragma unroll
    for (int bit = 0; bit < 4; ++bit) { av[bit] = pa[bit]; bv[bit] = pb[bit]; cv[bit] = pc[bit]; }
    const float dv = pd[0];

    const int y = tid & 127;
    const int zh = tid >> 7;       // 0/1 -> 16 z each

    u32 yw[4][8];
    float base = dv;
#pragma unroll
    for (int bit = 0; bit < 4; ++bit) {
        const uint4 q0 = ((const uint4*)sY)[bit * 256 + y * 2];
        const uint4 q1 = ((const uint4*)sY)[bit * 256 + y * 2 + 1];
        yw[bit][0] = q0.x; yw[bit][1] = q0.y; yw[bit][2] = q0.z; yw[bit][3] = q0.w;
        yw[bit][4] = q1.x; yw[bit][5] = q1.y; yw[bit][6] = q1.z; yw[bit][7] = q1.w;
        base += bv[bit] * (float)sYs[bit * 128 + y];
    }

    const int m = r * 128 + y;
#pragma unroll
    for (int zl2 = 0; zl2 < 16; ++zl2) {
        const int zl = zh * 16 + zl2;
        float wv = base;
#pragma unroll
        for (int bit = 0; bit < 4; ++bit) {
            const uint4 zw0 = ((const uint4*)sZ)[bit * 64 + zl * 2];
            const uint4 zw1 = ((const uint4*)sZ)[bit * 64 + zl * 2 + 1];
            int p = 0;
            p += __popc(yw[bit][0] & zw0.x);
            p += __popc(yw[bit][1] & zw0.y);
            p += __popc(yw[bit][2] & zw0.z);
            p += __popc(yw[bit][3] & zw0.w);
            p += __popc(yw[bit][4] & zw1.x);
            p += __popc(yw[bit][5] & zw1.y);
            p += __popc(yw[bit][6] & zw1.z);
            p += __popc(yw[bit][7] & zw1.w);
            wv += av[bit] * (float)p + cv[bit] * (float)sZs[bit * 32 + zl];
        }
        const int k = c * 128 + z0 + zl;
        Wb[(size_t)m * K_DIM + k] = __float2bfloat16(wv);
    }
}

// ---------------------------------------------------------------------------
// gemm_bias: out[M,N] = Xb[M,K] * Wb[N,K]^T + bias[N]   (bf16 MFMA, fp32 out)
//
// OCCUPANCY EXPERIMENT: 128(M) x 128(N) tile, BK=32, 256 threads = 4 waves
// (2M x 2N), per-wave 64x64 (acc 64 VGPR). Double-buffered LDS 2 x 16 KB =
// 32 KB -> with __launch_bounds__(256,4): 4 blocks/CU = 16 waves/CU
// (4/SIMD), 2x the wave-parallelism of all prior rounds (which were pinned
// at ~44 us with Occupancy 15%, MfmaUtil 30, VALUBusy 15 -- the
// latency-bound signature).
// Per K-tile t (2-phase counted-vmcnt, round-5-proven sync structure):
//   P1: 8 ds_read_b128 (a[0..3], b[0..3]); bar; lgkmcnt(0); prio1;
//       8 MFMA (a x b[0,1]); prio0; bar
//   P2: STAGE(t+2) (4 global_load_lds); vmcnt(4); bar; prio1;
//       8 MFMA (a x b[2,3]); prio0; bar
// WAR safety: P1's lgkm0 before its closing barrier drains all slot-s reads
// -> P2's overwriting stage is safe.
// vmcnt ledger (prologue fully drained by __syncthreads): before t's P2,
// queue = batch(t+1)[4]; P2 issues batch(t+2)[4] -> 8; vmcnt(4) retires
// batch(t+1), needed by tile t+1's P1. Tails 30/31: no stage, vmcnt(0).
// Swizzle (round-5 proven, BK=32): 1-KB slab = 16 rows x 4 chunks(16B);
// store chunk (l&3)^((l>>3)&3); read byte col cx=(fq^((fm>>1)&3))*16.
// Grid dim3(128,8): XCD = x%8 (128y === 0 mod 8) -> all 8 ntiles of an
// mtile on one XCD (A panel L2-shared); 128 blocks/XCD = 4/CU.
// ---------------------------------------------------------------------------
__device__ __forceinline__ void stage128(const u16* __restrict__ Xb,
        const u16* __restrict__ Wb, int m0, int n0, int kt, char* slot,
        int w, int lane, int srow, int csrc) {
#pragma unroll
    for (int j = 0; j < 2; ++j) {
        const int slab = w * 2 + j;               // 0..7
        const int row = slab * 16 + srow;         // 0..127
        load16_lds(Xb + (size_t)(m0 + row) * K_DIM + kt * 32 + csrc * 8,
                   slot + slab * 1024 + lane * 16);
    }
#pragma unroll
    for (int j = 0; j < 2; ++j) {
        const int slab = w * 2 + j;               // 0..7
        const int row = slab * 16 + srow;         // 0..127
        load16_lds(Wb + (size_t)(n0 + row) * K_DIM + kt * 32 + csrc * 8,
                   slot + 8192 + slab * 1024 + lane * 16);
    }
}

// VM: 4 -> vmcnt(4) steady; 0 -> vmcnt(0) (tail tiles).
template<bool DO_STAGE, int VM>
__device__ __forceinline__ void tile128(const char* __restrict__ slot,
        char* stslot, int ktg, floatx4 (&acc)[4][4],
        const u16* __restrict__ Xb, const u16* __restrict__ Wb,
        int m0, int n0, int w, int lane, int srow, int csrc,
        int wr, int wc, int fm, int cx) {
    const char* As = slot;
    const char* Bs = slot + 8192;
    short8 a[4], b[4];

    // ---- P1 ----
#pragma unroll
    for (int mi = 0; mi < 4; ++mi)
        a[mi] = *(const short8*)(As + (wr * 64 + mi * 16 + fm) * 64 + cx);
#pragma unroll
    for (int ni = 0; ni < 4; ++ni)
        b[ni] = *(const short8*)(Bs + (wc * 64 + ni * 16 + fm) * 64 + cx);
    __builtin_amdgcn_s_barrier();
    asm volatile("s_waitcnt lgkmcnt(0)" ::: "memory");
    __builtin_amdgcn_s_setprio(1);
#pragma unroll
    for (int mi = 0; mi < 4; ++mi) {
        acc[mi][0] = __builtin_amdgcn_mfma_f32_16x16x32_bf16(a[mi], b[0], acc[mi][0], 0, 0, 0);
        acc[mi][1] = __builtin_amdgcn_mfma_f32_16x16x32_bf16(a[mi], b[1], acc[mi][1], 0, 0, 0);
    }
    __builtin_amdgcn_s_setprio(0);
    __builtin_amdgcn_s_barrier();

    // ---- P2 ----
    if (DO_STAGE) stage128(Xb, Wb, m0, n0, ktg, stslot, w, lane, srow, csrc);
    if (VM == 4) asm volatile("s_waitcnt vmcnt(4)" ::: "memory");
    else         asm volatile("s_waitcnt vmcnt(0)" ::: "memory");
    __builtin_amdgcn_s_barrier();
    __builtin_amdgcn_s_setprio(1);
#pragma unroll
    for (int mi = 0; mi < 4; ++mi) {
        acc[mi][2] = __builtin_amdgcn_mfma_f32_16x16x32_bf16(a[mi], b[2], acc[mi][2], 0, 0, 0);
        acc[mi][3] = __builtin_amdgcn_mfma_f32_16x16x32_bf16(a[mi], b[3], acc[mi][3], 0, 0, 0);
    }
    __builtin_amdgcn_s_setprio(0);
    __builtin_amdgcn_s_barrier();
}

__global__ __launch_bounds__(256, 4) void gemm_bias(
        const u16* __restrict__ Xb, const u16* __restrict__ Wb,
        const float* __restrict__ bias, float* __restrict__ out) {
    __shared__ char lds[32768];    // slot s at s*16384: A[128][32] then B[128][32]

    const int tid = threadIdx.x;
    const int lane = tid & 63;
    const int w = tid >> 6;          // wave 0..3
    const int wr = w >> 1;           // 0..1 (M)
    const int wc = w & 1;            // 0..1 (N)
    const int m0 = blockIdx.x * 128;
    const int n0 = blockIdx.y * 128;

    // staging lane decomposition: 64 lanes cover one 1-KB slab (16r x 4c)
    const int srow = lane >> 2;                        // 0..15
    const int csrc = (lane & 3) ^ ((lane >> 3) & 3);   // swizzled source chunk
    // fragment lanes
    const int fm = lane & 15, fq = lane >> 4;
    const int cx = (fq ^ ((fm >> 1) & 3)) * 16;        // swizzled byte col

    char* slot0 = lds;
    char* slot1 = lds + 16384;

    floatx4 acc[4][4] = {};

    // prologue: tiles 0 (slot0), 1 (slot1); full drain + barrier (once).
    stage128(Xb, Wb, m0, n0, 0, slot0, w, lane, srow, csrc);
    stage128(Xb, Wb, m0, n0, 1, slot1, w, lane, srow, csrc);
    __syncthreads();   // drains vmcnt to 0; both prologue tiles resident

    for (int it = 0; it < 15; ++it) {
        tile128<true, 4>(slot0, slot0, 2 * it + 2, acc, Xb, Wb, m0, n0,
                         w, lane, srow, csrc, wr, wc, fm, cx);
        tile128<true, 4>(slot1, slot1, 2 * it + 3, acc, Xb, Wb, m0, n0,
                         w, lane, srow, csrc, wr, wc, fm, cx);
    }
    // tail: tiles 30, 31 -- no staging, conservative full drains
    tile128<false, 0>(slot0, slot0, 0, acc, Xb, Wb, m0, n0,
                      w, lane, srow, csrc, wr, wc, fm, cx);
    tile128<false, 0>(slot1, slot1, 0, acc, Xb, Wb, m0, n0,
                      w, lane, srow, csrc, wr, wc, fm, cx);

    // -----------------------------------------------------------------------
    // Epilogue: D layout col(N)=lane&15, row(M)=(lane>>4)*4+reg.
    // Per-wave private LDS slice (16 x EPW fp32): transpose to row-major,
    // store float4 (256 B contiguous per 16-lane group).
    // -----------------------------------------------------------------------
    float bias_r[4];
#pragma unroll
    for (int ni = 0; ni < 4; ++ni)
        bias_r[ni] = bias[n0 + wc * 64 + ni * 16 + fm];

    __syncthreads();   // all waves done with both slots; no vm loads pending
    float* ep = (float*)lds + w * (16 * EPW);   // 4352 B per wave, 17.4 KB total
    const int gm0 = m0 + wr * 64;
    const int gn0 = n0 + wc * 64;

#pragma unroll
    for (int mi = 0; mi < 4; ++mi) {
#pragma unroll
        for (int ni = 0; ni < 4; ++ni)
#pragma unroll
            for (int reg = 0; reg < 4; ++reg)
                ep[(fq * 4 + reg) * EPW + ni * 16 + fm] = acc[mi][ni][reg] + bias_r[ni];
#pragma unroll
        for (int t = 0; t < 4; ++t) {
            const int lr = t * 4 + fq;               // local row 0..15
            const float4 v = *(const float4*)(ep + lr * EPW + fm * 4);
            *(float4*)(out + (size_t)(gm0 + mi * 16 + lr) * N_DIM + gn0 + fm * 4) = v;
        }
        // wave-private slice; DS pipe is in-order per wave -> WAR safe
    }
}

// ---------------------------------------------------------------------------
extern "C" void kernel_launch(void* const* d_in, const int* in_sizes, int n_in,
                              void* d_out, int out_size, void* d_ws, size_t ws_size,
                              hipStream_t stream) {
    const float* X   = (const float*)d_in[0];
    const u32*   Yp  = (const u32*)d_in[1];
    const u32*   Zp  = (const u32*)d_in[2];
    const int*   Ys  = (const int*)d_in[3];
    const int*   Zs  = (const int*)d_in[4];
    const float* pa  = (const float*)d_in[5];
    const float* pb  = (const float*)d_in[6];
    const float* pc  = (const float*)d_in[7];
    const float* pd  = (const float*)d_in[8];
    const float* bias = (const float*)d_in[9];
    float* out = (float*)d_out;

    char* ws = (char*)d_ws;
    __hip_bfloat16* Wb = (__hip_bfloat16*)ws;                 // 2 MiB
    u16*            Xb = (u16*)(ws + (2u << 20));             // 32 MiB

    prep<<<8448, 256, 0, stream>>>(Yp, Zp, Ys, Zs, pa, pb, pc, pd, Wb,
                                   (const float4*)X, (ushort4*)Xb);
    gemm_bias<<<dim3(128, 8), 256, 0, stream>>>(Xb, (const u16*)Wb, bias, out);
}